// Round 7
// baseline (184.632 us; speedup 1.0000x reference)
//
#include <hip/hip_runtime.h>
#include <math.h>

// ---------------------------------------------------------------------------
// Problem constants
// ---------------------------------------------------------------------------
#define NROWS 65536          // B*NAG = 8192*8
#define NB    8192           // B
// workspace layout (float offsets)
#define STAT_OFF  0          // 8 replicas x 448 floats (contention /8)
#define WPACK_OFF 3584       // 6080 frags x 8 ushort
// d_out layout (float offsets): x_out, h, KL
#define OUT_XOUT 0
#define OUT_H    917504
#define OUT_KL   5111808

typedef __attribute__((ext_vector_type(8))) short bhalf8;
typedef __attribute__((ext_vector_type(4))) float floatx4;
typedef __attribute__((ext_vector_type(4))) unsigned short u16x4;
typedef __attribute__((ext_vector_type(4))) unsigned int u32x4;

__device__ __forceinline__ float sigmf(float x) { return 1.0f / (1.0f + __expf(-x)); }
__device__ __forceinline__ float tanhfast(float x) {
    x = fminf(fmaxf(x, -15.f), 15.f);
    float e = __expf(-2.f * x);
    return (1.f - e) / (1.f + e);
}
__device__ __forceinline__ unsigned short f2bf(float f) {   // RNE fp32->bf16
    unsigned int u = __float_as_uint(f);
    u += 0x7FFFu + ((u >> 16) & 1u);
    return (unsigned short)(u >> 16);
}
__device__ __forceinline__ float bf2f(unsigned short s) {
    return __uint_as_float(((unsigned int)s) << 16);
}
__device__ __forceinline__ bhalf8 pack8(float4 a, float4 b) {
    bhalf8 r;
    r[0] = (short)f2bf(a.x); r[1] = (short)f2bf(a.y);
    r[2] = (short)f2bf(a.z); r[3] = (short)f2bf(a.w);
    r[4] = (short)f2bf(b.x); r[5] = (short)f2bf(b.y);
    r[6] = (short)f2bf(b.z); r[7] = (short)f2bf(b.w);
    return r;
}

// fragment index maps (fold to constants under full unroll)
__device__ __forceinline__ int p2idx(int g, int i) {
    switch (i) {
        case 0:  return (0 + g) * 2 + 0;   case 1:  return (0 + g) * 2 + 1;
        case 2:  return (12 + g) * 2 + 0;  case 3:  return (12 + g) * 2 + 1;
        case 4:  return (4 + g) * 2 + 0;   case 5:  return (4 + g) * 2 + 1;
        case 6:  return (16 + g) * 2 + 0;  case 7:  return (16 + g) * 2 + 1;
        case 8:  return (8 + g) * 2 + 0;   case 9:  return (8 + g) * 2 + 1;
        case 10: return (20 + g) * 2 + 0;  default: return (20 + g) * 2 + 1;
    }
}
__device__ __forceinline__ int p3idx(int g, int i) {
    switch (i) {
        case 0: return g * 2 + 0;        case 1: return g * 2 + 1;
        case 2: return (4 + g) * 2 + 0;  case 3: return (4 + g) * 2 + 1;
        case 4: return (8 + g) * 2 + 0;  default: return (8 + g) * 2 + 1;
    }
}

// ---------------------------------------------------------------------------
// K0 (k_prep): zero stat accumulators + pack ALL weights (incl. po2) into
// bf16 MFMA B-fragment order.  95 blocks x 64 thr -> one fragment per thread.
// ---------------------------------------------------------------------------
__global__ void k_prep(const float* __restrict__ fc1_w,
                       const float* __restrict__ w_ih, const float* __restrict__ w_hh,
                       const float* __restrict__ aw1_w, const float* __restrict__ po1_w,
                       const float* __restrict__ aw2_w, const float* __restrict__ fc2_w,
                       const float* __restrict__ po2_w,
                       float* __restrict__ ws)
{
    const int t = threadIdx.x;
    if (blockIdx.x == 0)
        for (int i = t; i < 3584; i += 64) ws[STAT_OFF + i] = 0.f;

    unsigned short* wpk = (unsigned short*)(ws + WPACK_OFF);
    int f = blockIdx.x * 64 + t;
    if (f < 6080) {
        int lane, c, tile;
        const float* src;
        int colbase, krowstride, kofs = 0, kmax = 1 << 30, colmax = 16;
        if (f < 768) {            // wp1
            tile = f / 192; c = (f % 192) / 64; lane = f % 64;
            src = fc1_w; krowstride = 64; colbase = tile * 16;
        } else if (f < 3840) {    // wp2
            int f2 = f - 768;
            tile = f2 / 128; c = (f2 % 128) / 64; lane = f2 % 64;
            if (tile < 12) { src = w_ih; colbase = tile * 16; }
            else           { src = w_hh; colbase = (tile - 12) * 16; }
            krowstride = 192;
        } else if (f < 5376) {    // wp3
            int f3 = f - 3840;
            tile = f3 / 128; c = (f3 % 128) / 64; lane = f3 % 64;
            if (tile < 4)       { src = aw1_w; colbase = tile * 16; }
            else if (tile < 8)  { src = po1_w; colbase = (tile - 4) * 16; }
            else                { src = po1_w; colbase = (tile - 8) * 16; kofs = 64; }
            krowstride = 64;
        } else if (f < 5760) {    // wpa2
            int f4 = f - 5376;
            tile = f4 / 128; c = (f4 % 128) / 64; lane = f4 % 64;
            src = aw2_w; krowstride = 48; colbase = tile * 16;
        } else if (f < 5952) {    // wpf2
            int f5 = f - 5760;
            c = f5 / 64; lane = f5 % 64;
            src = fc2_w; krowstride = 14; colbase = 0;
            kmax = 88; colmax = 14;
        } else {                  // wpp2: po2_w [64][6] -> B-frags, K=64
            int f6 = f - 5952;
            c = f6 / 64; lane = f6 % 64;
            src = po2_w; krowstride = 6; colbase = 0;
            kmax = 64; colmax = 6;
        }
        int n = lane & 15, quad = lane >> 4;
        int col = colbase + n;
        unsigned short o[8];
        #pragma unroll
        for (int j = 0; j < 8; j++) {
            int k = c * 32 + quad * 8 + j + kofs;
            float v = (k < kmax && n < colmax) ? src[(size_t)k * krowstride + col] : 0.f;
            o[j] = f2bf(v);
        }
        u16x4 lo, hi;
        lo.x = o[0]; lo.y = o[1]; lo.z = o[2]; lo.w = o[3];
        hi.x = o[4]; hi.y = o[5]; hi.z = o[6]; hi.w = o[7];
        *(u16x4*)&wpk[f * 8]     = lo;
        *(u16x4*)&wpk[f * 8 + 4] = hi;
    }
}

// ---------------------------------------------------------------------------
// K1: fc1 -> GRU -> h + BN stat partials.  Round-7: 64 rows/block, grid 1024
// = 4 blocks/CU (occupancy ceiling 25%->50%) KEEPING the R3 ping-pong
// prefetch structure and a generous VGPR budget (launch_bounds(256,3)).
// R2's negative occupancy test was confounded (no prefetch, VGPR=64).
// Each wave owns ONE 16-row m-tile.  LDS 10.9 KB.
// ---------------------------------------------------------------------------
__global__ __launch_bounds__(256, 3) void k_front(
    const float* __restrict__ inp, const float* __restrict__ hin,
    const float* __restrict__ fc1_b,
    const float* __restrict__ b_ih, const float* __restrict__ b_hh,
    const float* __restrict__ aw1_b,
    float* __restrict__ h_out, float* __restrict__ ws)
{
    __shared__ __align__(16) unsigned short s_xb[64 * 80];  // x, then h (wave-private rows)
    __shared__ float s_stat[448];

    const int t = threadIdx.x;
    const int row0 = blockIdx.x * 64;
    const int lane = t & 63;
    const int w = t >> 6;          // wave owns rows w*16 .. w*16+15
    const int n16 = lane & 15;
    const int quad = lane >> 4;

    for (int i = t; i < 448; i += 256) s_stat[i] = 0.f;
    __syncthreads();

    const bhalf8* wp1 = (const bhalf8*)((const unsigned short*)(ws + WPACK_OFF));
    const bhalf8* wp2 = wp1 + 768;
    const bhalf8* wp3 = wp1 + 3840;

    // ---- A-frag direct global loads: inp (3 kchunks), h_in (2 kchunks) ----
    bhalf8 ai[3], ahf[2];
    {
        const float* gi = inp + (size_t)(row0 + w * 16 + n16) * 96 + quad * 8;
        #pragma unroll
        for (int kc = 0; kc < 3; kc++)
            ai[kc] = pack8(*(const float4*)&gi[kc * 32], *(const float4*)&gi[kc * 32 + 4]);
        const float* gh = hin + (size_t)(row0 + w * 16 + n16) * 64 + quad * 8;
        #pragma unroll
        for (int kc = 0; kc < 2; kc++)
            ahf[kc] = pack8(*(const float4*)&gh[kc * 32], *(const float4*)&gh[kc * 32 + 4]);
    }

    // ---- hoisted biases (independent scalar loads, issue early) ----
    float b1v[4], brv[4], bzv[4], binv[4], bhnv[4], abv[4];
    #pragma unroll
    for (int g = 0; g < 4; g++) {
        int col = g * 16 + n16;
        b1v[g]  = fc1_b[col];
        brv[g]  = b_ih[col] + b_hh[col];
        bzv[g]  = b_ih[64 + col] + b_hh[64 + col];
        binv[g] = b_ih[128 + col];
        bhnv[g] = b_hh[128 + col];
        abv[g]  = aw1_b[col];
    }

    // ---- P1: x = relu(inp @ fc1_w + b), frag double-buffer ----
    bhalf8 f1a[2][3];
    #pragma unroll
    for (int i = 0; i < 3; i++) f1a[0][i] = wp1[i * 64 + lane];
    #pragma unroll
    for (int g = 0; g < 4; g++) {
        const int cur = g & 1, nxt = cur ^ 1;
        if (g < 3) {
            #pragma unroll
            for (int i = 0; i < 3; i++) f1a[nxt][i] = wp1[((g + 1) * 3 + i) * 64 + lane];
        }
        int col = g * 16 + n16;
        floatx4 d = {0.f, 0.f, 0.f, 0.f};
        d = __builtin_amdgcn_mfma_f32_16x16x32_bf16(ai[0], f1a[cur][0], d, 0, 0, 0);
        d = __builtin_amdgcn_mfma_f32_16x16x32_bf16(ai[1], f1a[cur][1], d, 0, 0, 0);
        d = __builtin_amdgcn_mfma_f32_16x16x32_bf16(ai[2], f1a[cur][2], d, 0, 0, 0);
        #pragma unroll
        for (int q = 0; q < 4; q++)
            s_xb[(w * 16 + quad * 4 + q) * 80 + col] = f2bf(fmaxf(d[q] + b1v[g], 0.f));
    }

    // ---- issue P2 g=0 loads BEFORE the LDS x-read wait ----
    bhalf8 f2a[2][12];
    float hpv[2][4];
    #pragma unroll
    for (int i = 0; i < 12; i++) f2a[0][i] = wp2[p2idx(0, i) * 64 + lane];
    #pragma unroll
    for (int q = 0; q < 4; q++)
        hpv[0][q] = hin[(size_t)(row0 + w * 16 + quad * 4 + q) * 64 + n16];

    // x A-frags (own-wave rows; same-wave DS ordering makes this safe)
    bhalf8 ax[2];
    {
        int mr = w * 16 + n16;
        ax[0] = *(const bhalf8*)&s_xb[mr * 80 + 0  + quad * 8];
        ax[1] = *(const bhalf8*)&s_xb[mr * 80 + 32 + quad * 8];
    }

    // ---- P2: gates -> h; frag + hp double-buffer across g ----
    #pragma unroll
    for (int g = 0; g < 4; g++) {
        const int cur = g & 1, nxt = cur ^ 1;
        if (g < 3) {
            #pragma unroll
            for (int i = 0; i < 12; i++) f2a[nxt][i] = wp2[p2idx(g + 1, i) * 64 + lane];
            #pragma unroll
            for (int q = 0; q < 4; q++)
                hpv[nxt][q] = hin[(size_t)(row0 + w * 16 + quad * 4 + q) * 64 + (g + 1) * 16 + n16];
        }
        int col = g * 16 + n16;
        floatx4 dr, dz, dn, dh;
        {
            floatx4 d = {0.f, 0.f, 0.f, 0.f};
            d = __builtin_amdgcn_mfma_f32_16x16x32_bf16(ax[0], f2a[cur][0], d, 0, 0, 0);
            d = __builtin_amdgcn_mfma_f32_16x16x32_bf16(ax[1], f2a[cur][1], d, 0, 0, 0);
            d = __builtin_amdgcn_mfma_f32_16x16x32_bf16(ahf[0], f2a[cur][2], d, 0, 0, 0);
            d = __builtin_amdgcn_mfma_f32_16x16x32_bf16(ahf[1], f2a[cur][3], d, 0, 0, 0);
            dr = d;
            floatx4 e = {0.f, 0.f, 0.f, 0.f};
            e = __builtin_amdgcn_mfma_f32_16x16x32_bf16(ax[0], f2a[cur][4], e, 0, 0, 0);
            e = __builtin_amdgcn_mfma_f32_16x16x32_bf16(ax[1], f2a[cur][5], e, 0, 0, 0);
            e = __builtin_amdgcn_mfma_f32_16x16x32_bf16(ahf[0], f2a[cur][6], e, 0, 0, 0);
            e = __builtin_amdgcn_mfma_f32_16x16x32_bf16(ahf[1], f2a[cur][7], e, 0, 0, 0);
            dz = e;
            floatx4 f = {0.f, 0.f, 0.f, 0.f};
            f = __builtin_amdgcn_mfma_f32_16x16x32_bf16(ax[0], f2a[cur][8], f, 0, 0, 0);
            f = __builtin_amdgcn_mfma_f32_16x16x32_bf16(ax[1], f2a[cur][9], f, 0, 0, 0);
            dn = f;
            floatx4 h4 = {0.f, 0.f, 0.f, 0.f};
            h4 = __builtin_amdgcn_mfma_f32_16x16x32_bf16(ahf[0], f2a[cur][10], h4, 0, 0, 0);
            h4 = __builtin_amdgcn_mfma_f32_16x16x32_bf16(ahf[1], f2a[cur][11], h4, 0, 0, 0);
            dh = h4;
        }
        #pragma unroll
        for (int q = 0; q < 4; q++) {
            int lrow = w * 16 + quad * 4 + q;
            size_t grow = (size_t)(row0 + lrow);
            float r  = sigmf(dr[q] + brv[g]);
            float z  = sigmf(dz[q] + bzv[g]);
            float nt = tanhfast(dn[q] + binv[g] + r * (dh[q] + bhnv[g]));
            float hp = hpv[cur][q];
            float h  = (1.f - z) * nt + z * hp;
            h_out[grow * 64 + col] = h;
            s_xb[lrow * 80 + col] = f2bf(h);   // overlay x (x lives in ax regs)
        }
    }

    // ---- issue P3 g=0 loads BEFORE the LDS h-read wait ----
    bhalf8 f3a[2][6];
    #pragma unroll
    for (int i = 0; i < 6; i++) f3a[0][i] = wp3[p3idx(0, i) * 64 + lane];

    // h A-frags (own-wave rows)
    bhalf8 hh[2];
    {
        int mr = w * 16 + n16;
        hh[0] = *(const bhalf8*)&s_xb[mr * 80 + 0  + quad * 8];
        hh[1] = *(const bhalf8*)&s_xb[mr * 80 + 32 + quad * 8];
    }

    // ---- P3: a1/U/V stats; frag double-buffer across g ----
    #pragma unroll
    for (int g = 0; g < 4; g++) {
        const int cur = g & 1, nxt = cur ^ 1;
        if (g < 3) {
            #pragma unroll
            for (int i = 0; i < 6; i++) f3a[nxt][i] = wp3[p3idx(g + 1, i) * 64 + lane];
        }
        int col = g * 16 + n16;
        floatx4 da, du, dvv;
        {
            floatx4 d = {0.f, 0.f, 0.f, 0.f};
            d = __builtin_amdgcn_mfma_f32_16x16x32_bf16(hh[0], f3a[cur][0], d, 0, 0, 0);
            d = __builtin_amdgcn_mfma_f32_16x16x32_bf16(hh[1], f3a[cur][1], d, 0, 0, 0);
            da = d;
            floatx4 e = {0.f, 0.f, 0.f, 0.f};
            e = __builtin_amdgcn_mfma_f32_16x16x32_bf16(hh[0], f3a[cur][2], e, 0, 0, 0);
            e = __builtin_amdgcn_mfma_f32_16x16x32_bf16(hh[1], f3a[cur][3], e, 0, 0, 0);
            du = e;
            floatx4 f = {0.f, 0.f, 0.f, 0.f};
            f = __builtin_amdgcn_mfma_f32_16x16x32_bf16(hh[0], f3a[cur][4], f, 0, 0, 0);
            f = __builtin_amdgcn_mfma_f32_16x16x32_bf16(hh[1], f3a[cur][5], f, 0, 0, 0);
            dvv = f;
        }
        float ab = abv[g];
        float s1 = 0.f, s2 = 0.f, suq = 0.f, svq = 0.f;
        float su = 0.f, sv = 0.f;
        #pragma unroll
        for (int q = 0; q < 4; q++) {
            float a = da[q] + ab; s1 += a; s2 += a * a;
            float uv = du[q]; su += uv; suq += uv * uv;
            float vv = dvv[q]; sv += vv; svq += vv * vv;
        }
        {   // cross term per 8-row b-group (one 16-row tile = 2 groups)
            float u8 = su + __shfl_xor(su, 16, 64);
            float v8 = sv + __shfl_xor(sv, 16, 64);
            if ((quad & 1) == 0)
                atomicAdd(&s_stat[384 + col], u8 * v8 * (1.f / 64.f));
        }
        float t1 = s1 + __shfl_xor(s1, 16, 64);   t1 += __shfl_xor(t1, 32, 64);
        float t2 = s2 + __shfl_xor(s2, 16, 64);   t2 += __shfl_xor(t2, 32, 64);
        float t3 = su + __shfl_xor(su, 16, 64);   t3 += __shfl_xor(t3, 32, 64);
        float t4 = suq + __shfl_xor(suq, 16, 64); t4 += __shfl_xor(t4, 32, 64);
        float t5 = sv + __shfl_xor(sv, 16, 64);   t5 += __shfl_xor(t5, 32, 64);
        float t6 = svq + __shfl_xor(svq, 16, 64); t6 += __shfl_xor(t6, 32, 64);
        if (quad == 0) {
            atomicAdd(&s_stat[col], t1);
            atomicAdd(&s_stat[64 + col], t2);
            atomicAdd(&s_stat[128 + col], t3);
            atomicAdd(&s_stat[192 + col], t4);
            atomicAdd(&s_stat[256 + col], t5);
            atomicAdd(&s_stat[320 + col], t6);
        }
    }
    __syncthreads();
    if (t < 64) {
        float* gs = ws + STAT_OFF + (blockIdx.x & 7) * 448;   // 8 replicas
        #pragma unroll
        for (int q = 0; q < 7; q++)
            atomicAdd(&gs[q * 64 + t], s_stat[q * 64 + t]);
    }
}

// ---------------------------------------------------------------------------
// K2 (k_heads): fused stats-finalize + actor + critic head.  32 rows (4 b)
// per block, 128 thr.  (Unchanged from R5: MFMA phase C, XOR-16 swizzle.)
// ---------------------------------------------------------------------------
__global__ __launch_bounds__(128) void k_heads(
    const float* __restrict__ h_glob, const float* __restrict__ noise,
    const float* __restrict__ aw1_b, const float* __restrict__ aw2_b,
    const float* __restrict__ fc2_b, const float* __restrict__ po2_b,
    const float* __restrict__ aw_g, const float* __restrict__ aw_be,
    const float* __restrict__ po_g, const float* __restrict__ po_be,
    const float* __restrict__ po1_b,
    const float* __restrict__ ws, float* __restrict__ out)
{
    __shared__ __align__(16) unsigned short s_hb[32 * 104]; // h | c | zero-pad
    __shared__ __align__(16) unsigned short s_Ub[32 * 80];  // bf16 psc*U (swizzled cols)
    __shared__ __align__(16) unsigned short s_Vb[32 * 80];  // bf16 psc*V + psh (swizzled)
    __shared__ float s_ms[32 * 52];                         // mu | sigma (padded stride)
    __shared__ __align__(16) float s_out[32 * 48];          // s_ab (bf16, str 80) then out
    __shared__ __align__(16) float s_dv[256];               // asc ash psc psh
    __shared__ float s_kl[32];

    const int t = threadIdx.x;
    const int row0 = blockIdx.x * 32;
    const int b0 = blockIdx.x * 4;
    const int lane = t & 63;
    const int w = t >> 6;
    const int n16 = lane & 15;
    const int quad = lane >> 4;
    const int mrow = w * 16 + n16;

    // ---- derive BN scale/shift from global stats (sum 8 replicas) ----
    if (t < 64) {
        const float* st = ws + STAT_OFF;
        float sa = 0.f, sb = 0.f, sc = 0.f, sd = 0.f, se = 0.f, sf = 0.f, sg = 0.f;
        #pragma unroll
        for (int r = 0; r < 8; r++) {
            const float* sr = st + r * 448;
            sa += sr[t];       sb += sr[64 + t];  sc += sr[128 + t];
            sd += sr[192 + t]; se += sr[256 + t]; sf += sr[320 + t];
            sg += sr[384 + t];
        }
        const float invN = 1.f / 65536.f;
        float am = sa * invN;
        float av = sb * invN - am * am;
        float asc = aw_g[t] * rsqrtf(av + 1e-5f);
        s_dv[t] = asc;
        s_dv[64 + t] = aw_be[t] - asc * am;
        float Eu = sc * invN;
        float vu = sd * invN - Eu * Eu;
        float Ev = se * invN;
        float vv = sf * invN - Ev * Ev;
        float cov = sg * (1.f / 8192.f) - Eu * Ev;
        float my = Eu + Ev + po1_b[t];
        float vy = vu + vv + 2.f * cov;
        float psc = po_g[t] * rsqrtf(vy + 1e-5f);
        s_dv[128 + t] = psc;
        s_dv[192 + t] = po_be[t] + psc * (po1_b[t] - my);
    }

    const bhalf8* wp3  = ((const bhalf8*)((const unsigned short*)(ws + WPACK_OFF))) + 3840;
    const bhalf8* wpa2 = wp3 + 1536;
    const bhalf8* wpf2 = wpa2 + 384;
    const bhalf8* wpp2 = wpf2 + 192;

    // ---- hoisted global scalars (issue early, independent) ----
    float abv[4];
    #pragma unroll
    for (int g = 0; g < 4; g++) abv[g] = aw1_b[g * 16 + n16];
    float p2bv = (n16 < 6) ? po2_b[n16] : 0.f;

    // ---- stage h -> bf16 (cols 0-63); zero pad cols 88-95 ----
    {
        const float* gh = h_glob + (size_t)row0 * 64;
        for (int i = t; i < 512; i += 128) {
            int r = i >> 4, c4 = (i & 15) * 4;
            float4 v = *(const float4*)&gh[r * 64 + c4];
            u16x4 p; p.x = f2bf(v.x); p.y = f2bf(v.y); p.z = f2bf(v.z); p.w = f2bf(v.w);
            *(u16x4*)&s_hb[r * 104 + c4] = p;
        }
        for (int i = t; i < 64; i += 128) {
            int r = i >> 1, c4 = 88 + (i & 1) * 4;
            u16x4 z; z.x = 0; z.y = 0; z.z = 0; z.w = 0;
            *(u16x4*)&s_hb[r * 104 + c4] = z;
        }
    }

    // ---- prefetch phase-A g=0 frags before the barrier wait ----
    bhalf8 fA[2][6];
    #pragma unroll
    for (int i = 0; i < 6; i++) fA[0][i] = wp3[p3idx(0, i) * 64 + lane];

    __syncthreads();

    unsigned short* s_ab = (unsigned short*)s_out;    // stride 80 swizzled, dead before C

    // ---- hoisted BN scalars from s_dv (post-barrier) ----
    float ascv[4], ashv[4], pscv[4], pshv[4];
    #pragma unroll
    for (int g = 0; g < 4; g++) {
        int col = g * 16 + n16;
        ascv[g] = s_dv[col];       ashv[g] = s_dv[64 + col];
        pscv[g] = s_dv[128 + col]; pshv[g] = s_dv[192 + col];
    }

    // ---- phase A: a1/U'/V' via MFMA; frag double-buffer; swizzled stores ----
    {
        bhalf8 ah0 = *(const bhalf8*)&s_hb[mrow * 104 + 0  + quad * 8];
        bhalf8 ah1 = *(const bhalf8*)&s_hb[mrow * 104 + 32 + quad * 8];
        #pragma unroll
        for (int g = 0; g < 4; g++) {
            const int cur = g & 1, nxt = cur ^ 1;
            if (g < 3) {
                #pragma unroll
                for (int i = 0; i < 6; i++) fA[nxt][i] = wp3[p3idx(g + 1, i) * 64 + lane];
            }
            int col = g * 16 + n16;
            floatx4 da = {0.f, 0.f, 0.f, 0.f}, duu = {0.f, 0.f, 0.f, 0.f}, dvv = {0.f, 0.f, 0.f, 0.f};
            da  = __builtin_amdgcn_mfma_f32_16x16x32_bf16(ah0, fA[cur][0], da, 0, 0, 0);
            da  = __builtin_amdgcn_mfma_f32_16x16x32_bf16(ah1, fA[cur][1], da, 0, 0, 0);
            duu = __builtin_amdgcn_mfma_f32_16x16x32_bf16(ah0, fA[cur][2], duu, 0, 0, 0);
            duu = __builtin_amdgcn_mfma_f32_16x16x32_bf16(ah1, fA[cur][3], duu, 0, 0, 0);
            dvv = __builtin_amdgcn_mfma_f32_16x16x32_bf16(ah0, fA[cur][4], dvv, 0, 0, 0);
            dvv = __builtin_amdgcn_mfma_f32_16x16x32_bf16(ah1, fA[cur][5], dvv, 0, 0, 0);
            // row = w*16 + quad*4 + q  ->  (row>>2)&3 == quad  ->  swz = col ^ (quad<<4)
            int scol = col ^ (quad << 4);
            #pragma unroll
            for (int q = 0; q < 4; q++) {
                int lrow = w * 16 + quad * 4 + q;
                s_ab[lrow * 80 + scol] = f2bf(fmaxf(ascv[g] * (da[q] + abv[g]) + ashv[g], 0.f));
                s_Ub[lrow * 80 + scol] = f2bf(pscv[g] * duu[q]);
                s_Vb[lrow * 80 + scol] = f2bf(pscv[g] * dvv[q] + pshv[g]);
            }
        }
    }
    // s_ab read below is own-wave rows -> no barrier

    // ---- phase B1: aw = a @ aw2_w + b -> mu / sigma; frag prefetch ----
    {
        bhalf8 fB[2][2];
        fB[0][0] = wpa2[0 * 64 + lane];
        fB[0][1] = wpa2[1 * 64 + lane];
        float bbv[3];
        #pragma unroll
        for (int g = 0; g < 3; g++) bbv[g] = aw2_b[g * 16 + n16];

        // A-frag read row = mrow -> swz nibble = (n16>>2)&3
        int anib = ((n16 >> 2) & 3) << 4;
        bhalf8 aa0 = *(const bhalf8*)&s_ab[mrow * 80 + ((0  + quad * 8) ^ anib)];
        bhalf8 aa1 = *(const bhalf8*)&s_ab[mrow * 80 + ((32 + quad * 8) ^ anib)];
        #pragma unroll
        for (int g = 0; g < 3; g++) {
            const int cur = g & 1, nxt = cur ^ 1;
            if (g < 2) {
                fB[nxt][0] = wpa2[((g + 1) * 2 + 0) * 64 + lane];
                fB[nxt][1] = wpa2[((g + 1) * 2 + 1) * 64 + lane];
            }
            floatx4 d = {0.f, 0.f, 0.f, 0.f};
            d = __builtin_amdgcn_mfma_f32_16x16x32_bf16(aa0, fB[cur][0], d, 0, 0, 0);
            d = __builtin_amdgcn_mfma_f32_16x16x32_bf16(aa1, fB[cur][1], d, 0, 0, 0);
            int col = g * 16 + n16;
            #pragma unroll
            for (int q = 0; q < 4; q++) {
                int lrow = w * 16 + quad * 4 + q;
                float v = d[q] + bbv[g];
                s_ms[lrow * 52 + col] = (col < 24) ? v : fmaxf(__expf(v), 0.2f);
            }
        }
    }

    // ---- prefetch B3 + phase-C frags before the barriers ----
    bhalf8 ff[3];
    ff[0] = wpf2[0 * 64 + lane];
    ff[1] = wpf2[1 * 64 + lane];
    ff[2] = wpf2[2 * 64 + lane];
    bhalf8 w0 = wpp2[0 * 64 + lane];
    bhalf8 w1 = wpp2[1 * 64 + lane];

    __syncthreads();

    // ---- phase B2: c = mu + sqrt(sigma)*noise -> s_hb cols 64-87 (bf16) ----
    for (int i = t; i < 768; i += 128) {
        int r = i / 24, m = i - r * 24;
        float c = s_ms[r * 52 + m] + sqrtf(s_ms[r * 52 + 24 + m]) * noise[(size_t)(row0 + r) * 24 + m];
        s_hb[r * 104 + 64 + m] = f2bf(c);
    }
    __syncthreads();

    // ---- phase B3: x_out = [h,c] @ fc2_w + b ----
    {
        bhalf8 hc0 = *(const bhalf8*)&s_hb[mrow * 104 + 0  + quad * 8];
        bhalf8 hc1 = *(const bhalf8*)&s_hb[mrow * 104 + 32 + quad * 8];
        bhalf8 hc2 = *(const bhalf8*)&s_hb[mrow * 104 + 64 + quad * 8];
        floatx4 d = {0.f, 0.f, 0.f, 0.f};
        d = __builtin_amdgcn_mfma_f32_16x16x32_bf16(hc0, ff[0], d, 0, 0, 0);
        d = __builtin_amdgcn_mfma_f32_16x16x32_bf16(hc1, ff[1], d, 0, 0, 0);
        d = __builtin_amdgcn_mfma_f32_16x16x32_bf16(hc2, ff[2], d, 0, 0, 0);
        if (n16 < 14) {
            float bb = fc2_b[n16];
            float* xout = out + OUT_XOUT;
            #pragma unroll
            for (int q = 0; q < 4; q++) {
                size_t grow = (size_t)(row0 + w * 16 + quad * 4 + q);
                xout[grow * 14 + n16] = d[q] + bb;
            }
        }
    }
    __syncthreads();   // s_ab dead -> s_out overlay safe; s_Ub/s_Vb visible

    // ---- phase C: critic pairwise via MFMA (p built in-reg, bf16) ----
    // p[pair=bl*64+i*8+j][c] = relu(U[bl*8+j][c] + V[bl*8+i][c]); out = p @ po2
    {
        #pragma unroll
        for (int tt = 0; tt < 8; tt++) {
            int tile = w * 8 + tt;
            int p = tile * 16 + n16;               // A-supply row for this lane
            int bl = p >> 6, ii = (p >> 3) & 7, jj = p & 7;
            int ru = bl * 8 + jj, rv = bl * 8 + ii;
            int nu = ((ru >> 2) & 3) << 4, nv = ((rv >> 2) & 3) << 4;
            floatx4 d = {0.f, 0.f, 0.f, 0.f};
            #pragma unroll
            for (int kc = 0; kc < 2; kc++) {
                bhalf8 u8 = *(const bhalf8*)&s_Ub[ru * 80 + ((kc * 32 + quad * 8) ^ nu)];
                bhalf8 v8 = *(const bhalf8*)&s_Vb[rv * 80 + ((kc * 32 + quad * 8) ^ nv)];
                u32x4 pw;
                #pragma unroll
                for (int m = 0; m < 8; m += 2) {
                    float lo = fmaxf(bf2f((unsigned short)u8[m])     + bf2f((unsigned short)v8[m]),     0.f);
                    float hi = fmaxf(bf2f((unsigned short)u8[m + 1]) + bf2f((unsigned short)v8[m + 1]), 0.f);
                    unsigned int pk;
                    asm("v_cvt_pk_bf16_f32 %0, %1, %2" : "=v"(pk) : "v"(lo), "v"(hi));
                    pw[m >> 1] = pk;
                }
                bhalf8 pa = __builtin_bit_cast(bhalf8, pw);
                d = __builtin_amdgcn_mfma_f32_16x16x32_bf16(pa, kc == 0 ? w0 : w1, d, 0, 0, 0);
            }
            if (n16 < 6) {
                #pragma unroll
                for (int q = 0; q < 4; q++) {
                    int pr = tile * 16 + quad * 4 + q;     // output pair-row
                    int obl = pr >> 6, oi = (pr >> 3) & 7, oj = pr & 7;
                    s_out[(obl * 8 + oi) * 48 + oj * 6 + n16] = d[q] + p2bv;
                }
            }
        }
    }
    __syncthreads();

    // ---- KL ----
    if (t < 32) {
        float s = 0.f;
        #pragma unroll 4
        for (int m = 0; m < 24; m++) {
            float mu0 = s_ms[t * 52 + m];
            float sg0 = s_ms[t * 52 + 24 + m];
            float mu1 = s_out[t * 48 + m];
            float sg1 = fmaxf(__expf(s_out[t * 48 + 24 + m]), 0.2f);
            float d0 = mu0 - mu1;
            s += __logf(sg1 / sg0) + (sg0 + d0 * d0) / sg1 - 1.f;
        }
        s_kl[t] = s;
    }
    __syncthreads();
    if (t < 4) {
        float s = 0.f;
        #pragma unroll
        for (int i = 0; i < 8; i++) s += s_kl[t * 8 + i];
        out[OUT_KL + b0 + t] = s * (0.5f / 192.f);
    }
}

// ---------------------------------------------------------------------------
extern "C" void kernel_launch(void* const* d_in, const int* in_sizes, int n_in,
                              void* d_out, int out_size, void* d_ws, size_t ws_size,
                              hipStream_t stream)
{
    (void)in_sizes; (void)n_in; (void)out_size; (void)ws_size;
    const float* inp   = (const float*)d_in[0];
    const float* hin   = (const float*)d_in[1];
    const float* noise = (const float*)d_in[2];
    const float* fc1_w = (const float*)d_in[3];
    const float* fc1_b = (const float*)d_in[4];
    const float* w_ih  = (const float*)d_in[5];
    const float* w_hh  = (const float*)d_in[6];
    const float* b_ih  = (const float*)d_in[7];
    const float* b_hh  = (const float*)d_in[8];
    const float* aw1_w = (const float*)d_in[9];
    const float* aw1_b = (const float*)d_in[10];
    const float* aw_g  = (const float*)d_in[11];
    const float* aw_be = (const float*)d_in[12];
    const float* aw2_w = (const float*)d_in[13];
    const float* aw2_b = (const float*)d_in[14];
    const float* po1_w = (const float*)d_in[15];
    const float* po1_b = (const float*)d_in[16];
    const float* po_g  = (const float*)d_in[17];
    const float* po_be = (const float*)d_in[18];
    const float* po2_w = (const float*)d_in[19];
    const float* po2_b = (const float*)d_in[20];
    const float* fc2_w = (const float*)d_in[21];
    const float* fc2_b = (const float*)d_in[22];
    float* out = (float*)d_out;
    float* ws  = (float*)d_ws;

    hipLaunchKernelGGL(k_prep,  dim3(95),   dim3(64), 0, stream,
                       fc1_w, w_ih, w_hh, aw1_w, po1_w, aw2_w, fc2_w, po2_w, ws);
    hipLaunchKernelGGL(k_front, dim3(1024), dim3(256), 0, stream,
                       inp, hin, fc1_b, b_ih, b_hh, aw1_b, out + OUT_H, ws);
    hipLaunchKernelGGL(k_heads, dim3(2048), dim3(128), 0, stream,
                       out + OUT_H, noise, aw1_b, aw2_b, fc2_b, po2_b,
                       aw_g, aw_be, po_g, po_be, po1_b, ws, out);
}

// Round 8
// 173.624 us; speedup vs baseline: 1.0634x; 1.0634x over previous
//
#include <hip/hip_runtime.h>
#include <math.h>

// ---------------------------------------------------------------------------
// Problem constants
// ---------------------------------------------------------------------------
#define NROWS 65536          // B*NAG = 8192*8
#define NB    8192           // B
// workspace layout (float offsets)
#define STAT_OFF  0          // 8 replicas x 448 floats (contention /8)
#define WPACK_OFF 3584       // 6080 frags x 8 ushort
// d_out layout (float offsets): x_out, h, KL
#define OUT_XOUT 0
#define OUT_H    917504
#define OUT_KL   5111808

typedef __attribute__((ext_vector_type(8))) short bhalf8;
typedef __attribute__((ext_vector_type(4))) float floatx4;
typedef __attribute__((ext_vector_type(4))) unsigned short u16x4;
typedef __attribute__((ext_vector_type(4))) unsigned int u32x4;

__device__ __forceinline__ float sigmf(float x) { return 1.0f / (1.0f + __expf(-x)); }
__device__ __forceinline__ float tanhfast(float x) {
    x = fminf(fmaxf(x, -15.f), 15.f);
    float e = __expf(-2.f * x);
    return (1.f - e) / (1.f + e);
}
__device__ __forceinline__ unsigned short f2bf(float f) {   // RNE fp32->bf16
    unsigned int u = __float_as_uint(f);
    u += 0x7FFFu + ((u >> 16) & 1u);
    return (unsigned short)(u >> 16);
}
__device__ __forceinline__ float bf2f(unsigned short s) {
    return __uint_as_float(((unsigned int)s) << 16);
}
__device__ __forceinline__ bhalf8 pack8(float4 a, float4 b) {
    bhalf8 r;
    r[0] = (short)f2bf(a.x); r[1] = (short)f2bf(a.y);
    r[2] = (short)f2bf(a.z); r[3] = (short)f2bf(a.w);
    r[4] = (short)f2bf(b.x); r[5] = (short)f2bf(b.y);
    r[6] = (short)f2bf(b.z); r[7] = (short)f2bf(b.w);
    return r;
}

// fragment index maps (fold to constants under full unroll)
__device__ __forceinline__ int p2idx(int g, int i) {
    switch (i) {
        case 0:  return (0 + g) * 2 + 0;   case 1:  return (0 + g) * 2 + 1;
        case 2:  return (12 + g) * 2 + 0;  case 3:  return (12 + g) * 2 + 1;
        case 4:  return (4 + g) * 2 + 0;   case 5:  return (4 + g) * 2 + 1;
        case 6:  return (16 + g) * 2 + 0;  case 7:  return (16 + g) * 2 + 1;
        case 8:  return (8 + g) * 2 + 0;   case 9:  return (8 + g) * 2 + 1;
        case 10: return (20 + g) * 2 + 0;  default: return (20 + g) * 2 + 1;
    }
}
__device__ __forceinline__ int p3idx(int g, int i) {
    switch (i) {
        case 0: return g * 2 + 0;        case 1: return g * 2 + 1;
        case 2: return (4 + g) * 2 + 0;  case 3: return (4 + g) * 2 + 1;
        case 4: return (8 + g) * 2 + 0;  default: return (8 + g) * 2 + 1;
    }
}

// ---------------------------------------------------------------------------
// K0 (k_prep): zero stat accumulators + pack ALL weights (incl. po2) into
// bf16 MFMA B-fragment order.  95 blocks x 64 thr -> one fragment per thread.
// ---------------------------------------------------------------------------
__global__ void k_prep(const float* __restrict__ fc1_w,
                       const float* __restrict__ w_ih, const float* __restrict__ w_hh,
                       const float* __restrict__ aw1_w, const float* __restrict__ po1_w,
                       const float* __restrict__ aw2_w, const float* __restrict__ fc2_w,
                       const float* __restrict__ po2_w,
                       float* __restrict__ ws)
{
    const int t = threadIdx.x;
    if (blockIdx.x == 0)
        for (int i = t; i < 3584; i += 64) ws[STAT_OFF + i] = 0.f;

    unsigned short* wpk = (unsigned short*)(ws + WPACK_OFF);
    int f = blockIdx.x * 64 + t;
    if (f < 6080) {
        int lane, c, tile;
        const float* src;
        int colbase, krowstride, kofs = 0, kmax = 1 << 30, colmax = 16;
        if (f < 768) {            // wp1
            tile = f / 192; c = (f % 192) / 64; lane = f % 64;
            src = fc1_w; krowstride = 64; colbase = tile * 16;
        } else if (f < 3840) {    // wp2
            int f2 = f - 768;
            tile = f2 / 128; c = (f2 % 128) / 64; lane = f2 % 64;
            if (tile < 12) { src = w_ih; colbase = tile * 16; }
            else           { src = w_hh; colbase = (tile - 12) * 16; }
            krowstride = 192;
        } else if (f < 5376) {    // wp3
            int f3 = f - 3840;
            tile = f3 / 128; c = (f3 % 128) / 64; lane = f3 % 64;
            if (tile < 4)       { src = aw1_w; colbase = tile * 16; }
            else if (tile < 8)  { src = po1_w; colbase = (tile - 4) * 16; }
            else                { src = po1_w; colbase = (tile - 8) * 16; kofs = 64; }
            krowstride = 64;
        } else if (f < 5760) {    // wpa2
            int f4 = f - 5376;
            tile = f4 / 128; c = (f4 % 128) / 64; lane = f4 % 64;
            src = aw2_w; krowstride = 48; colbase = tile * 16;
        } else if (f < 5952) {    // wpf2
            int f5 = f - 5760;
            c = f5 / 64; lane = f5 % 64;
            src = fc2_w; krowstride = 14; colbase = 0;
            kmax = 88; colmax = 14;
        } else {                  // wpp2: po2_w [64][6] -> B-frags, K=64
            int f6 = f - 5952;
            c = f6 / 64; lane = f6 % 64;
            src = po2_w; krowstride = 6; colbase = 0;
            kmax = 64; colmax = 6;
        }
        int n = lane & 15, quad = lane >> 4;
        int col = colbase + n;
        unsigned short o[8];
        #pragma unroll
        for (int j = 0; j < 8; j++) {
            int k = c * 32 + quad * 8 + j + kofs;
            float v = (k < kmax && n < colmax) ? src[(size_t)k * krowstride + col] : 0.f;
            o[j] = f2bf(v);
        }
        u16x4 lo, hi;
        lo.x = o[0]; lo.y = o[1]; lo.z = o[2]; lo.w = o[3];
        hi.x = o[4]; hi.y = o[5]; hi.z = o[6]; hi.w = o[7];
        *(u16x4*)&wpk[f * 8]     = lo;
        *(u16x4*)&wpk[f * 8 + 4] = hi;
    }
}

// ---------------------------------------------------------------------------
// K1: fc1 -> GRU -> h + BN stat partials.  REVERTED to the proven-best R4/R6
// shape: 128 rows/block, 256 thr (4 waves, 2 m-tiles/wave), grid 512,
// __launch_bounds__(256,2), frag+hp ping-pong prefetch, 8-replica stat merge.
// Two independent A/B tests (R2, R7) showed 64-row blocks regress ~+8 us:
// per-block fixed costs dominate; occupancy is not the limiter.
// ---------------------------------------------------------------------------
__global__ __launch_bounds__(256, 2) void k_front(
    const float* __restrict__ inp, const float* __restrict__ hin,
    const float* __restrict__ fc1_b,
    const float* __restrict__ b_ih, const float* __restrict__ b_hh,
    const float* __restrict__ aw1_b,
    float* __restrict__ h_out, float* __restrict__ ws)
{
    __shared__ __align__(16) unsigned short s_xb[128 * 80];  // x, then h (wave-private rows)
    __shared__ float s_stat[448];

    const int t = threadIdx.x;
    const int row0 = blockIdx.x * 128;
    const int lane = t & 63;
    const int w = t >> 6;
    const int n16 = lane & 15;
    const int quad = lane >> 4;

    for (int i = t; i < 448; i += 256) s_stat[i] = 0.f;
    __syncthreads();

    const bhalf8* wp1 = (const bhalf8*)((const unsigned short*)(ws + WPACK_OFF));
    const bhalf8* wp2 = wp1 + 768;
    const bhalf8* wp3 = wp1 + 3840;

    // ---- A-frag direct global loads: inp (3 kchunks), h_in (2 kchunks) ----
    bhalf8 ai[2][3], ahf[2][2];
    #pragma unroll
    for (int u = 0; u < 2; u++) {
        const float* gi = inp + (size_t)(row0 + w * 32 + u * 16 + n16) * 96 + quad * 8;
        #pragma unroll
        for (int kc = 0; kc < 3; kc++)
            ai[u][kc] = pack8(*(const float4*)&gi[kc * 32], *(const float4*)&gi[kc * 32 + 4]);
        const float* gh = hin + (size_t)(row0 + w * 32 + u * 16 + n16) * 64 + quad * 8;
        #pragma unroll
        for (int kc = 0; kc < 2; kc++)
            ahf[u][kc] = pack8(*(const float4*)&gh[kc * 32], *(const float4*)&gh[kc * 32 + 4]);
    }

    // ---- hoisted biases (independent scalar loads, issue early) ----
    float b1v[4], brv[4], bzv[4], binv[4], bhnv[4], abv[4];
    #pragma unroll
    for (int g = 0; g < 4; g++) {
        int col = g * 16 + n16;
        b1v[g]  = fc1_b[col];
        brv[g]  = b_ih[col] + b_hh[col];
        bzv[g]  = b_ih[64 + col] + b_hh[64 + col];
        binv[g] = b_ih[128 + col];
        bhnv[g] = b_hh[128 + col];
        abv[g]  = aw1_b[col];
    }

    // ---- P1: x = relu(inp @ fc1_w + b), frag double-buffer ----
    bhalf8 f1a[2][3];
    #pragma unroll
    for (int i = 0; i < 3; i++) f1a[0][i] = wp1[i * 64 + lane];
    #pragma unroll
    for (int g = 0; g < 4; g++) {
        const int cur = g & 1, nxt = cur ^ 1;
        if (g < 3) {
            #pragma unroll
            for (int i = 0; i < 3; i++) f1a[nxt][i] = wp1[((g + 1) * 3 + i) * 64 + lane];
        }
        int col = g * 16 + n16;
        #pragma unroll
        for (int u = 0; u < 2; u++) {
            floatx4 d = {0.f, 0.f, 0.f, 0.f};
            d = __builtin_amdgcn_mfma_f32_16x16x32_bf16(ai[u][0], f1a[cur][0], d, 0, 0, 0);
            d = __builtin_amdgcn_mfma_f32_16x16x32_bf16(ai[u][1], f1a[cur][1], d, 0, 0, 0);
            d = __builtin_amdgcn_mfma_f32_16x16x32_bf16(ai[u][2], f1a[cur][2], d, 0, 0, 0);
            #pragma unroll
            for (int q = 0; q < 4; q++)
                s_xb[(w * 32 + u * 16 + quad * 4 + q) * 80 + col] = f2bf(fmaxf(d[q] + b1v[g], 0.f));
        }
    }

    // ---- issue P2 g=0 loads BEFORE the LDS x-read wait ----
    bhalf8 f2a[2][12];
    float hpv[2][8];
    #pragma unroll
    for (int i = 0; i < 12; i++) f2a[0][i] = wp2[p2idx(0, i) * 64 + lane];
    #pragma unroll
    for (int u = 0; u < 2; u++)
        #pragma unroll
        for (int q = 0; q < 4; q++)
            hpv[0][u * 4 + q] = hin[(size_t)(row0 + w * 32 + u * 16 + quad * 4 + q) * 64 + n16];

    // x A-frags (own-wave rows; same-wave DS ordering makes this safe)
    bhalf8 ax[2][2];
    #pragma unroll
    for (int u = 0; u < 2; u++) {
        int mr = w * 32 + u * 16 + n16;
        ax[u][0] = *(const bhalf8*)&s_xb[mr * 80 + 0  + quad * 8];
        ax[u][1] = *(const bhalf8*)&s_xb[mr * 80 + 32 + quad * 8];
    }

    // ---- P2: gates -> h; frag + hp double-buffer across g ----
    #pragma unroll
    for (int g = 0; g < 4; g++) {
        const int cur = g & 1, nxt = cur ^ 1;
        if (g < 3) {
            #pragma unroll
            for (int i = 0; i < 12; i++) f2a[nxt][i] = wp2[p2idx(g + 1, i) * 64 + lane];
            #pragma unroll
            for (int u = 0; u < 2; u++)
                #pragma unroll
                for (int q = 0; q < 4; q++)
                    hpv[nxt][u * 4 + q] = hin[(size_t)(row0 + w * 32 + u * 16 + quad * 4 + q) * 64 + (g + 1) * 16 + n16];
        }
        int col = g * 16 + n16;
        floatx4 dr[2], dz[2], dn[2], dh[2];
        #pragma unroll
        for (int u = 0; u < 2; u++) {
            floatx4 d = {0.f, 0.f, 0.f, 0.f};
            d = __builtin_amdgcn_mfma_f32_16x16x32_bf16(ax[u][0], f2a[cur][0], d, 0, 0, 0);
            d = __builtin_amdgcn_mfma_f32_16x16x32_bf16(ax[u][1], f2a[cur][1], d, 0, 0, 0);
            d = __builtin_amdgcn_mfma_f32_16x16x32_bf16(ahf[u][0], f2a[cur][2], d, 0, 0, 0);
            d = __builtin_amdgcn_mfma_f32_16x16x32_bf16(ahf[u][1], f2a[cur][3], d, 0, 0, 0);
            dr[u] = d;
            floatx4 e = {0.f, 0.f, 0.f, 0.f};
            e = __builtin_amdgcn_mfma_f32_16x16x32_bf16(ax[u][0], f2a[cur][4], e, 0, 0, 0);
            e = __builtin_amdgcn_mfma_f32_16x16x32_bf16(ax[u][1], f2a[cur][5], e, 0, 0, 0);
            e = __builtin_amdgcn_mfma_f32_16x16x32_bf16(ahf[u][0], f2a[cur][6], e, 0, 0, 0);
            e = __builtin_amdgcn_mfma_f32_16x16x32_bf16(ahf[u][1], f2a[cur][7], e, 0, 0, 0);
            dz[u] = e;
            floatx4 f = {0.f, 0.f, 0.f, 0.f};
            f = __builtin_amdgcn_mfma_f32_16x16x32_bf16(ax[u][0], f2a[cur][8], f, 0, 0, 0);
            f = __builtin_amdgcn_mfma_f32_16x16x32_bf16(ax[u][1], f2a[cur][9], f, 0, 0, 0);
            dn[u] = f;
            floatx4 h4 = {0.f, 0.f, 0.f, 0.f};
            h4 = __builtin_amdgcn_mfma_f32_16x16x32_bf16(ahf[u][0], f2a[cur][10], h4, 0, 0, 0);
            h4 = __builtin_amdgcn_mfma_f32_16x16x32_bf16(ahf[u][1], f2a[cur][11], h4, 0, 0, 0);
            dh[u] = h4;
        }
        #pragma unroll
        for (int u = 0; u < 2; u++) {
            #pragma unroll
            for (int q = 0; q < 4; q++) {
                int lrow = w * 32 + u * 16 + quad * 4 + q;
                size_t grow = (size_t)(row0 + lrow);
                float r  = sigmf(dr[u][q] + brv[g]);
                float z  = sigmf(dz[u][q] + bzv[g]);
                float nt = tanhfast(dn[u][q] + binv[g] + r * (dh[u][q] + bhnv[g]));
                float hp = hpv[cur][u * 4 + q];
                float h  = (1.f - z) * nt + z * hp;
                h_out[grow * 64 + col] = h;
                s_xb[lrow * 80 + col] = f2bf(h);   // overlay x (x lives in ax regs)
            }
        }
    }

    // ---- issue P3 g=0 loads BEFORE the LDS h-read wait ----
    bhalf8 f3a[2][6];
    #pragma unroll
    for (int i = 0; i < 6; i++) f3a[0][i] = wp3[p3idx(0, i) * 64 + lane];

    // h A-frags (own-wave rows)
    bhalf8 hh[2][2];
    #pragma unroll
    for (int u = 0; u < 2; u++) {
        int mr = w * 32 + u * 16 + n16;
        hh[u][0] = *(const bhalf8*)&s_xb[mr * 80 + 0  + quad * 8];
        hh[u][1] = *(const bhalf8*)&s_xb[mr * 80 + 32 + quad * 8];
    }

    // ---- P3: a1/U/V stats; frag double-buffer across g ----
    #pragma unroll
    for (int g = 0; g < 4; g++) {
        const int cur = g & 1, nxt = cur ^ 1;
        if (g < 3) {
            #pragma unroll
            for (int i = 0; i < 6; i++) f3a[nxt][i] = wp3[p3idx(g + 1, i) * 64 + lane];
        }
        int col = g * 16 + n16;
        floatx4 da[2], du[2], dvv[2];
        #pragma unroll
        for (int u = 0; u < 2; u++) {
            floatx4 d = {0.f, 0.f, 0.f, 0.f};
            d = __builtin_amdgcn_mfma_f32_16x16x32_bf16(hh[u][0], f3a[cur][0], d, 0, 0, 0);
            d = __builtin_amdgcn_mfma_f32_16x16x32_bf16(hh[u][1], f3a[cur][1], d, 0, 0, 0);
            da[u] = d;
            floatx4 e = {0.f, 0.f, 0.f, 0.f};
            e = __builtin_amdgcn_mfma_f32_16x16x32_bf16(hh[u][0], f3a[cur][2], e, 0, 0, 0);
            e = __builtin_amdgcn_mfma_f32_16x16x32_bf16(hh[u][1], f3a[cur][3], e, 0, 0, 0);
            du[u] = e;
            floatx4 f = {0.f, 0.f, 0.f, 0.f};
            f = __builtin_amdgcn_mfma_f32_16x16x32_bf16(hh[u][0], f3a[cur][4], f, 0, 0, 0);
            f = __builtin_amdgcn_mfma_f32_16x16x32_bf16(hh[u][1], f3a[cur][5], f, 0, 0, 0);
            dvv[u] = f;
        }
        float ab = abv[g];
        float s1 = 0.f, s2 = 0.f, suq = 0.f, svq = 0.f;
        float su[2] = {0.f, 0.f}, sv[2] = {0.f, 0.f};
        #pragma unroll
        for (int u = 0; u < 2; u++) {
            #pragma unroll
            for (int q = 0; q < 4; q++) {
                float a = da[u][q] + ab; s1 += a; s2 += a * a;
                float uv = du[u][q]; su[u] += uv; suq += uv * uv;
                float vv = dvv[u][q]; sv[u] += vv; svq += vv * vv;
            }
        }
        #pragma unroll
        for (int u = 0; u < 2; u++) {      // cross term per 8-row b-group
            float u8 = su[u] + __shfl_xor(su[u], 16, 64);
            float v8 = sv[u] + __shfl_xor(sv[u], 16, 64);
            if ((quad & 1) == 0)
                atomicAdd(&s_stat[384 + col], u8 * v8 * (1.f / 64.f));
        }
        float sut = su[0] + su[1];
        float svt = sv[0] + sv[1];
        float t1 = s1 + __shfl_xor(s1, 16, 64);   t1 += __shfl_xor(t1, 32, 64);
        float t2 = s2 + __shfl_xor(s2, 16, 64);   t2 += __shfl_xor(t2, 32, 64);
        float t3 = sut + __shfl_xor(sut, 16, 64); t3 += __shfl_xor(t3, 32, 64);
        float t4 = suq + __shfl_xor(suq, 16, 64); t4 += __shfl_xor(t4, 32, 64);
        float t5 = svt + __shfl_xor(svt, 16, 64); t5 += __shfl_xor(t5, 32, 64);
        float t6 = svq + __shfl_xor(svq, 16, 64); t6 += __shfl_xor(t6, 32, 64);
        if (quad == 0) {
            atomicAdd(&s_stat[col], t1);
            atomicAdd(&s_stat[64 + col], t2);
            atomicAdd(&s_stat[128 + col], t3);
            atomicAdd(&s_stat[192 + col], t4);
            atomicAdd(&s_stat[256 + col], t5);
            atomicAdd(&s_stat[320 + col], t6);
        }
    }
    __syncthreads();
    if (t < 64) {
        float* gs = ws + STAT_OFF + (blockIdx.x & 7) * 448;   // 8 replicas
        #pragma unroll
        for (int q = 0; q < 7; q++)
            atomicAdd(&gs[q * 64 + t], s_stat[q * 64 + t]);
    }
}

// ---------------------------------------------------------------------------
// K2 (k_heads): fused stats-finalize + actor + critic head.  32 rows (4 b)
// per block, 128 thr.  Round-8: B2 restructured to OWN-WAVE rows (wave w
// handles rows 16w..16w+15) -> B1->B2->B3 are pure same-wave DS ordering,
// removing TWO __syncthreads from the serial chain; noise prefetched at
// kernel start (24 B/lane, coalesced) instead of loading between barriers.
// ---------------------------------------------------------------------------
__global__ __launch_bounds__(128) void k_heads(
    const float* __restrict__ h_glob, const float* __restrict__ noise,
    const float* __restrict__ aw1_b, const float* __restrict__ aw2_b,
    const float* __restrict__ fc2_b, const float* __restrict__ po2_b,
    const float* __restrict__ aw_g, const float* __restrict__ aw_be,
    const float* __restrict__ po_g, const float* __restrict__ po_be,
    const float* __restrict__ po1_b,
    const float* __restrict__ ws, float* __restrict__ out)
{
    __shared__ __align__(16) unsigned short s_hb[32 * 104]; // h | c | zero-pad
    __shared__ __align__(16) unsigned short s_Ub[32 * 80];  // bf16 psc*U (swizzled cols)
    __shared__ __align__(16) unsigned short s_Vb[32 * 80];  // bf16 psc*V + psh (swizzled)
    __shared__ float s_ms[32 * 52];                         // mu | sigma (padded stride)
    __shared__ __align__(16) float s_out[32 * 48];          // s_ab (bf16, str 80) then out
    __shared__ __align__(16) float s_dv[256];               // asc ash psc psh
    __shared__ float s_kl[32];

    const int t = threadIdx.x;
    const int row0 = blockIdx.x * 32;
    const int b0 = blockIdx.x * 4;
    const int lane = t & 63;
    const int w = t >> 6;
    const int n16 = lane & 15;
    const int quad = lane >> 4;
    const int mrow = w * 16 + n16;

    // ---- prefetch noise early (own-wave rows; 6 contiguous floats/lane) ----
    float nz[6];
    {
        const float* np = noise + (size_t)(row0 + w * 16) * 24 + lane * 6;
        #pragma unroll
        for (int j = 0; j < 6; j++) nz[j] = np[j];
    }

    // ---- derive BN scale/shift from global stats (sum 8 replicas) ----
    if (t < 64) {
        const float* st = ws + STAT_OFF;
        float sa = 0.f, sb = 0.f, sc = 0.f, sd = 0.f, se = 0.f, sf = 0.f, sg = 0.f;
        #pragma unroll
        for (int r = 0; r < 8; r++) {
            const float* sr = st + r * 448;
            sa += sr[t];       sb += sr[64 + t];  sc += sr[128 + t];
            sd += sr[192 + t]; se += sr[256 + t]; sf += sr[320 + t];
            sg += sr[384 + t];
        }
        const float invN = 1.f / 65536.f;
        float am = sa * invN;
        float av = sb * invN - am * am;
        float asc = aw_g[t] * rsqrtf(av + 1e-5f);
        s_dv[t] = asc;
        s_dv[64 + t] = aw_be[t] - asc * am;
        float Eu = sc * invN;
        float vu = sd * invN - Eu * Eu;
        float Ev = se * invN;
        float vv = sf * invN - Ev * Ev;
        float cov = sg * (1.f / 8192.f) - Eu * Ev;
        float my = Eu + Ev + po1_b[t];
        float vy = vu + vv + 2.f * cov;
        float psc = po_g[t] * rsqrtf(vy + 1e-5f);
        s_dv[128 + t] = psc;
        s_dv[192 + t] = po_be[t] + psc * (po1_b[t] - my);
    }

    const bhalf8* wp3  = ((const bhalf8*)((const unsigned short*)(ws + WPACK_OFF))) + 3840;
    const bhalf8* wpa2 = wp3 + 1536;
    const bhalf8* wpf2 = wpa2 + 384;
    const bhalf8* wpp2 = wpf2 + 192;

    // ---- hoisted global scalars (issue early, independent) ----
    float abv[4];
    #pragma unroll
    for (int g = 0; g < 4; g++) abv[g] = aw1_b[g * 16 + n16];
    float p2bv = (n16 < 6) ? po2_b[n16] : 0.f;

    // ---- stage h -> bf16 (cols 0-63); zero pad cols 88-95 ----
    {
        const float* gh = h_glob + (size_t)row0 * 64;
        for (int i = t; i < 512; i += 128) {
            int r = i >> 4, c4 = (i & 15) * 4;
            float4 v = *(const float4*)&gh[r * 64 + c4];
            u16x4 p; p.x = f2bf(v.x); p.y = f2bf(v.y); p.z = f2bf(v.z); p.w = f2bf(v.w);
            *(u16x4*)&s_hb[r * 104 + c4] = p;
        }
        for (int i = t; i < 64; i += 128) {
            int r = i >> 1, c4 = 88 + (i & 1) * 4;
            u16x4 z; z.x = 0; z.y = 0; z.z = 0; z.w = 0;
            *(u16x4*)&s_hb[r * 104 + c4] = z;
        }
    }

    // ---- prefetch phase-A g=0 frags before the barrier wait ----
    bhalf8 fA[2][6];
    #pragma unroll
    for (int i = 0; i < 6; i++) fA[0][i] = wp3[p3idx(0, i) * 64 + lane];

    __syncthreads();

    unsigned short* s_ab = (unsigned short*)s_out;    // stride 80 swizzled, dead before C

    // ---- hoisted BN scalars from s_dv (post-barrier) ----
    float ascv[4], ashv[4], pscv[4], pshv[4];
    #pragma unroll
    for (int g = 0; g < 4; g++) {
        int col = g * 16 + n16;
        ascv[g] = s_dv[col];       ashv[g] = s_dv[64 + col];
        pscv[g] = s_dv[128 + col]; pshv[g] = s_dv[192 + col];
    }

    // ---- phase A: a1/U'/V' via MFMA; frag double-buffer; swizzled stores ----
    {
        bhalf8 ah0 = *(const bhalf8*)&s_hb[mrow * 104 + 0  + quad * 8];
        bhalf8 ah1 = *(const bhalf8*)&s_hb[mrow * 104 + 32 + quad * 8];
        #pragma unroll
        for (int g = 0; g < 4; g++) {
            const int cur = g & 1, nxt = cur ^ 1;
            if (g < 3) {
                #pragma unroll
                for (int i = 0; i < 6; i++) fA[nxt][i] = wp3[p3idx(g + 1, i) * 64 + lane];
            }
            int col = g * 16 + n16;
            floatx4 da = {0.f, 0.f, 0.f, 0.f}, duu = {0.f, 0.f, 0.f, 0.f}, dvv = {0.f, 0.f, 0.f, 0.f};
            da  = __builtin_amdgcn_mfma_f32_16x16x32_bf16(ah0, fA[cur][0], da, 0, 0, 0);
            da  = __builtin_amdgcn_mfma_f32_16x16x32_bf16(ah1, fA[cur][1], da, 0, 0, 0);
            duu = __builtin_amdgcn_mfma_f32_16x16x32_bf16(ah0, fA[cur][2], duu, 0, 0, 0);
            duu = __builtin_amdgcn_mfma_f32_16x16x32_bf16(ah1, fA[cur][3], duu, 0, 0, 0);
            dvv = __builtin_amdgcn_mfma_f32_16x16x32_bf16(ah0, fA[cur][4], dvv, 0, 0, 0);
            dvv = __builtin_amdgcn_mfma_f32_16x16x32_bf16(ah1, fA[cur][5], dvv, 0, 0, 0);
            // row = w*16 + quad*4 + q  ->  (row>>2)&3 == quad  ->  swz = col ^ (quad<<4)
            int scol = col ^ (quad << 4);
            #pragma unroll
            for (int q = 0; q < 4; q++) {
                int lrow = w * 16 + quad * 4 + q;
                s_ab[lrow * 80 + scol] = f2bf(fmaxf(ascv[g] * (da[q] + abv[g]) + ashv[g], 0.f));
                s_Ub[lrow * 80 + scol] = f2bf(pscv[g] * duu[q]);
                s_Vb[lrow * 80 + scol] = f2bf(pscv[g] * dvv[q] + pshv[g]);
            }
        }
    }
    // s_ab read below is own-wave rows -> no barrier

    // ---- phase B1: aw = a @ aw2_w + b -> mu / sigma; frag prefetch ----
    {
        bhalf8 fB[2][2];
        fB[0][0] = wpa2[0 * 64 + lane];
        fB[0][1] = wpa2[1 * 64 + lane];
        float bbv[3];
        #pragma unroll
        for (int g = 0; g < 3; g++) bbv[g] = aw2_b[g * 16 + n16];

        // A-frag read row = mrow -> swz nibble = (n16>>2)&3
        int anib = ((n16 >> 2) & 3) << 4;
        bhalf8 aa0 = *(const bhalf8*)&s_ab[mrow * 80 + ((0  + quad * 8) ^ anib)];
        bhalf8 aa1 = *(const bhalf8*)&s_ab[mrow * 80 + ((32 + quad * 8) ^ anib)];
        #pragma unroll
        for (int g = 0; g < 3; g++) {
            const int cur = g & 1, nxt = cur ^ 1;
            if (g < 2) {
                fB[nxt][0] = wpa2[((g + 1) * 2 + 0) * 64 + lane];
                fB[nxt][1] = wpa2[((g + 1) * 2 + 1) * 64 + lane];
            }
            floatx4 d = {0.f, 0.f, 0.f, 0.f};
            d = __builtin_amdgcn_mfma_f32_16x16x32_bf16(aa0, fB[cur][0], d, 0, 0, 0);
            d = __builtin_amdgcn_mfma_f32_16x16x32_bf16(aa1, fB[cur][1], d, 0, 0, 0);
            int col = g * 16 + n16;
            #pragma unroll
            for (int q = 0; q < 4; q++) {
                int lrow = w * 16 + quad * 4 + q;
                float v = d[q] + bbv[g];
                s_ms[lrow * 52 + col] = (col < 24) ? v : fmaxf(__expf(v), 0.2f);
            }
        }
    }

    // ---- prefetch B3 + phase-C frags ----
    bhalf8 ff[3];
    ff[0] = wpf2[0 * 64 + lane];
    ff[1] = wpf2[1 * 64 + lane];
    ff[2] = wpf2[2 * 64 + lane];
    bhalf8 w0 = wpp2[0 * 64 + lane];
    bhalf8 w1 = wpp2[1 * 64 + lane];

    // ---- phase B2 (OWN-WAVE rows, no barrier): c = mu + sqrt(sigma)*noise ----
    // wave w covers rows 16w..16w+15: e = lane*6+j in [0,384) -> r = w*16+e/24
    #pragma unroll
    for (int j = 0; j < 6; j++) {
        int e = lane * 6 + j;
        int r = w * 16 + e / 24, m = e % 24;
        float c = s_ms[r * 52 + m] + sqrtf(s_ms[r * 52 + 24 + m]) * nz[j];
        s_hb[r * 104 + 64 + m] = f2bf(c);
    }

    // ---- phase B3 (own-wave rows, no barrier): x_out = [h,c] @ fc2_w + b ----
    {
        bhalf8 hc0 = *(const bhalf8*)&s_hb[mrow * 104 + 0  + quad * 8];
        bhalf8 hc1 = *(const bhalf8*)&s_hb[mrow * 104 + 32 + quad * 8];
        bhalf8 hc2 = *(const bhalf8*)&s_hb[mrow * 104 + 64 + quad * 8];
        floatx4 d = {0.f, 0.f, 0.f, 0.f};
        d = __builtin_amdgcn_mfma_f32_16x16x32_bf16(hc0, ff[0], d, 0, 0, 0);
        d = __builtin_amdgcn_mfma_f32_16x16x32_bf16(hc1, ff[1], d, 0, 0, 0);
        d = __builtin_amdgcn_mfma_f32_16x16x32_bf16(hc2, ff[2], d, 0, 0, 0);
        if (n16 < 14) {
            float bb = fc2_b[n16];
            float* xout = out + OUT_XOUT;
            #pragma unroll
            for (int q = 0; q < 4; q++) {
                size_t grow = (size_t)(row0 + w * 16 + quad * 4 + q);
                xout[grow * 14 + n16] = d[q] + bb;
            }
        }
    }
    __syncthreads();   // s_ab dead -> s_out overlay safe; s_Ub/s_Vb cross-wave visible

    // ---- phase C: critic pairwise via MFMA (p built in-reg, bf16) ----
    // p[pair=bl*64+i*8+j][c] = relu(U[bl*8+j][c] + V[bl*8+i][c]); out = p @ po2
    {
        #pragma unroll
        for (int tt = 0; tt < 8; tt++) {
            int tile = w * 8 + tt;
            int p = tile * 16 + n16;               // A-supply row for this lane
            int bl = p >> 6, ii = (p >> 3) & 7, jj = p & 7;
            int ru = bl * 8 + jj, rv = bl * 8 + ii;
            int nu = ((ru >> 2) & 3) << 4, nv = ((rv >> 2) & 3) << 4;
            floatx4 d = {0.f, 0.f, 0.f, 0.f};
            #pragma unroll
            for (int kc = 0; kc < 2; kc++) {
                bhalf8 u8 = *(const bhalf8*)&s_Ub[ru * 80 + ((kc * 32 + quad * 8) ^ nu)];
                bhalf8 v8 = *(const bhalf8*)&s_Vb[rv * 80 + ((kc * 32 + quad * 8) ^ nv)];
                u32x4 pw;
                #pragma unroll
                for (int m = 0; m < 8; m += 2) {
                    float lo = fmaxf(bf2f((unsigned short)u8[m])     + bf2f((unsigned short)v8[m]),     0.f);
                    float hi = fmaxf(bf2f((unsigned short)u8[m + 1]) + bf2f((unsigned short)v8[m + 1]), 0.f);
                    unsigned int pk;
                    asm("v_cvt_pk_bf16_f32 %0, %1, %2" : "=v"(pk) : "v"(lo), "v"(hi));
                    pw[m >> 1] = pk;
                }
                bhalf8 pa = __builtin_bit_cast(bhalf8, pw);
                d = __builtin_amdgcn_mfma_f32_16x16x32_bf16(pa, kc == 0 ? w0 : w1, d, 0, 0, 0);
            }
            if (n16 < 6) {
                #pragma unroll
                for (int q = 0; q < 4; q++) {
                    int pr = tile * 16 + quad * 4 + q;     // output pair-row
                    int obl = pr >> 6, oi = (pr >> 3) & 7, oj = pr & 7;
                    s_out[(obl * 8 + oi) * 48 + oj * 6 + n16] = d[q] + p2bv;
                }
            }
        }
    }
    __syncthreads();

    // ---- KL ----
    if (t < 32) {
        float s = 0.f;
        #pragma unroll 4
        for (int m = 0; m < 24; m++) {
            float mu0 = s_ms[t * 52 + m];
            float sg0 = s_ms[t * 52 + 24 + m];
            float mu1 = s_out[t * 48 + m];
            float sg1 = fmaxf(__expf(s_out[t * 48 + 24 + m]), 0.2f);
            float d0 = mu0 - mu1;
            s += __logf(sg1 / sg0) + (sg0 + d0 * d0) / sg1 - 1.f;
        }
        s_kl[t] = s;
    }
    __syncthreads();
    if (t < 4) {
        float s = 0.f;
        #pragma unroll
        for (int i = 0; i < 8; i++) s += s_kl[t * 8 + i];
        out[OUT_KL + b0 + t] = s * (0.5f / 192.f);
    }
}

// ---------------------------------------------------------------------------
extern "C" void kernel_launch(void* const* d_in, const int* in_sizes, int n_in,
                              void* d_out, int out_size, void* d_ws, size_t ws_size,
                              hipStream_t stream)
{
    (void)in_sizes; (void)n_in; (void)out_size; (void)ws_size;
    const float* inp   = (const float*)d_in[0];
    const float* hin   = (const float*)d_in[1];
    const float* noise = (const float*)d_in[2];
    const float* fc1_w = (const float*)d_in[3];
    const float* fc1_b = (const float*)d_in[4];
    const float* w_ih  = (const float*)d_in[5];
    const float* w_hh  = (const float*)d_in[6];
    const float* b_ih  = (const float*)d_in[7];
    const float* b_hh  = (const float*)d_in[8];
    const float* aw1_w = (const float*)d_in[9];
    const float* aw1_b = (const float*)d_in[10];
    const float* aw_g  = (const float*)d_in[11];
    const float* aw_be = (const float*)d_in[12];
    const float* aw2_w = (const float*)d_in[13];
    const float* aw2_b = (const float*)d_in[14];
    const float* po1_w = (const float*)d_in[15];
    const float* po1_b = (const float*)d_in[16];
    const float* po_g  = (const float*)d_in[17];
    const float* po_be = (const float*)d_in[18];
    const float* po2_w = (const float*)d_in[19];
    const float* po2_b = (const float*)d_in[20];
    const float* fc2_w = (const float*)d_in[21];
    const float* fc2_b = (const float*)d_in[22];
    float* out = (float*)d_out;
    float* ws  = (float*)d_ws;

    hipLaunchKernelGGL(k_prep,  dim3(95),   dim3(64), 0, stream,
                       fc1_w, w_ih, w_hh, aw1_w, po1_w, aw2_w, fc2_w, po2_w, ws);
    hipLaunchKernelGGL(k_front, dim3(512),  dim3(256), 0, stream,
                       inp, hin, fc1_b, b_ih, b_hh, aw1_b, out + OUT_H, ws);
    hipLaunchKernelGGL(k_heads, dim3(2048), dim3(128), 0, stream,
                       out + OUT_H, noise, aw1_b, aw2_b, fc2_b, po2_b,
                       aw_g, aw_be, po_g, po_be, po1_b, ws, out);
}